// Round 1
// baseline (237.939 us; speedup 1.0000x reference)
//
#include <hip/hip_runtime.h>

// Attention_22325240004782 — additive attention (show-attend-tell style)
// B=64, L=196, D=2048, A=1024. Dominant cost: af@W_att (52.7 GFLOP) -> bf16 MFMA.

typedef unsigned short u16;
typedef u16 u16x8 __attribute__((ext_vector_type(8)));
typedef __bf16 bf16x8 __attribute__((ext_vector_type(8)));
typedef float f32x4 __attribute__((ext_vector_type(4)));

#define B_ 64
#define L_ 196
#define D_ 2048
#define A_ 1024
#define M_ (B_ * L_)  // 12544 = 98 * 128

__device__ __forceinline__ u16 f2bf(float x) {
  unsigned u = __float_as_uint(x);
  unsigned r = (u + 0x7fffu + ((u >> 16) & 1u)) >> 16;  // RNE
  return (u16)r;
}

__device__ __forceinline__ float tanh_fast(float x) {
  float e = __expf(2.0f * x);
  return 1.0f - 2.0f / (e + 1.0f);  // exact at +/-inf, ~1e-6 abs err
}

// ---- W_att [D][A] fp32 -> WT [A][D] bf16 (k-contiguous for MFMA B-frags) ----
__global__ __launch_bounds__(256) void transpose_w_k(const float* __restrict__ W,
                                                     u16* __restrict__ WT) {
  __shared__ float t[32][33];
  int n0 = blockIdx.x * 32, k0 = blockIdx.y * 32;
  int tx = threadIdx.x, ty = threadIdx.y;  // 32 x 8
#pragma unroll
  for (int i = 0; i < 4; ++i)
    t[ty + i * 8][tx] = W[(size_t)(k0 + ty + i * 8) * A_ + n0 + tx];
  __syncthreads();
#pragma unroll
  for (int i = 0; i < 4; ++i)
    WT[(size_t)(n0 + ty + i * 8) * D_ + k0 + tx] = f2bf(t[tx][ty + i * 8]);
}

// ---- ph[b][a] = sum_d h[b][d] * W_h[d][a]  (biases folded into GEMM epilogue) ----
// grid (4 a-groups, 8 b-groups, 8 d-chunks), 256 thr. Split-K via atomics.
__global__ __launch_bounds__(256) void ph_k(const float* __restrict__ h,
                                            const float* __restrict__ Wh,
                                            float* __restrict__ ph) {
  __shared__ float hs[8 * 256];
  int ag = blockIdx.x, bg = blockIdx.y, dc = blockIdx.z;
  int t = threadIdx.x;
  int d0 = dc * 256;
  for (int i = t; i < 2048; i += 256)
    hs[i] = h[(size_t)(bg * 8 + (i >> 8)) * D_ + d0 + (i & 255)];
  __syncthreads();
  int a = ag * 256 + t;
  float acc[8] = {};
  for (int d = 0; d < 256; ++d) {
    float wv = Wh[(size_t)(d0 + d) * A_ + a];
#pragma unroll
    for (int bb = 0; bb < 8; ++bb) acc[bb] += hs[bb * 256 + d] * wv;
  }
#pragma unroll
  for (int bb = 0; bb < 8; ++bb)
    atomicAdd(&ph[(size_t)(bg * 8 + bb) * A_ + a], acc[bb]);
}

// ---- main GEMM: P = af(bf16) @ W_att(bf16), fused tanh-score epilogue ----
// 128x128 tile, BK=32, 4 waves (2x2), each wave 64x64 (4x4 frags of 16x16x32).
__global__ __launch_bounds__(256) void gemm_score_k(
    const float* __restrict__ af, const u16* __restrict__ WT,
    const float* __restrict__ ph, const float* __restrict__ batt,
    const float* __restrict__ bh, const float* __restrict__ walpha,
    float* __restrict__ scores) {
  __shared__ u16 As[128 * 32];
  __shared__ u16 Bs[128 * 32];
  const int tid = threadIdx.x;
  const int lane = tid & 63;
  const int wid = tid >> 6;
  const int wr = wid >> 1, wc = wid & 1;
  const int m0 = blockIdx.y * 128;
  const int n0 = blockIdx.x * 128;
  const int fr = lane & 15, fq = lane >> 4;

  f32x4 acc[4][4] = {};

  const int ar = tid >> 3, akq = tid & 7;  // A: 4 rows x float4 per thread
  const int br = tid >> 2, bkc = tid & 3;  // B: 2 rows x 8-bf16 per thread
  const float* aptr = af + (size_t)(m0 + ar) * D_ + akq * 4;
  const u16* bptr = WT + (size_t)(n0 + br) * D_ + bkc * 8;

  for (int k0 = 0; k0 < D_; k0 += 32) {
    // stage A (fp32 -> bf16) and B (bf16 copy) into linear [row][32k] tiles
#pragma unroll
    for (int i = 0; i < 4; ++i) {
      float4 v = *(const float4*)(aptr + (size_t)i * 32 * D_ + k0);
      ushort4 p;
      p.x = f2bf(v.x); p.y = f2bf(v.y); p.z = f2bf(v.z); p.w = f2bf(v.w);
      *(ushort4*)&As[(ar + i * 32) * 32 + akq * 4] = p;
    }
#pragma unroll
    for (int i = 0; i < 2; ++i) {
      u16x8 v = *(const u16x8*)(bptr + (size_t)i * 64 * D_ + k0);
      *(u16x8*)&Bs[(br + i * 64) * 32 + bkc * 8] = v;
    }
    __syncthreads();
    u16x8 arg[4], brg[4];
#pragma unroll
    for (int mi = 0; mi < 4; ++mi)
      arg[mi] = *(const u16x8*)&As[(wr * 64 + mi * 16 + fr) * 32 + fq * 8];
#pragma unroll
    for (int ni = 0; ni < 4; ++ni)
      brg[ni] = *(const u16x8*)&Bs[(wc * 64 + ni * 16 + fr) * 32 + fq * 8];
#pragma unroll
    for (int mi = 0; mi < 4; ++mi)
#pragma unroll
      for (int ni = 0; ni < 4; ++ni)
        acc[mi][ni] = __builtin_amdgcn_mfma_f32_16x16x32_bf16(
            __builtin_bit_cast(bf16x8, arg[mi]),
            __builtin_bit_cast(bf16x8, brg[ni]), acc[mi][ni], 0, 0, 0);
    __syncthreads();
  }

  // epilogue: p = acc + ph[b] + b_att + b_h; score partial = tanh(p)*w_alpha
#pragma unroll
  for (int mi = 0; mi < 4; ++mi) {
#pragma unroll
    for (int r = 0; r < 4; ++r) {
      const int gm = m0 + wr * 64 + mi * 16 + fq * 4 + r;
      const int bb = gm / L_;
      const float* phrow = ph + (size_t)bb * A_;
      float sp = 0.f;
#pragma unroll
      for (int ni = 0; ni < 4; ++ni) {
        const int gn = n0 + wc * 64 + ni * 16 + fr;
        float p = acc[mi][ni][r] + phrow[gn] + batt[gn] + bh[gn];
        sp += tanh_fast(p) * walpha[gn];
      }
      sp += __shfl_xor(sp, 1);
      sp += __shfl_xor(sp, 2);
      sp += __shfl_xor(sp, 4);
      sp += __shfl_xor(sp, 8);
      if (fr == 0) atomicAdd(&scores[gm], sp);
    }
  }
}

// ---- softmax over L=196 per batch ----
__global__ __launch_bounds__(256) void softmax_k(const float* __restrict__ scores,
                                                 float* __restrict__ wout) {
  __shared__ float red[4];
  int b = blockIdx.x, t = threadIdx.x;
  float s = (t < L_) ? scores[b * L_ + t] : -1e30f;
  float m = s;
#pragma unroll
  for (int o = 32; o; o >>= 1) m = fmaxf(m, __shfl_xor(m, o));
  if ((t & 63) == 0) red[t >> 6] = m;
  __syncthreads();
  m = fmaxf(fmaxf(red[0], red[1]), fmaxf(red[2], red[3]));
  float e = (t < L_) ? __expf(s - m) : 0.f;
  float sum = e;
#pragma unroll
  for (int o = 32; o; o >>= 1) sum += __shfl_xor(sum, o);
  __syncthreads();
  if ((t & 63) == 0) red[t >> 6] = sum;
  __syncthreads();
  sum = red[0] + red[1] + red[2] + red[3];
  if (t < L_) wout[b * L_ + t] = e / sum;
}

// ---- weighted[b][d] = sum_l w[b][l] * af[b][l][d] ----
// grid (8 d-groups of 64 float4, 64 b), 256 thr = 4 L-quarters x 64 d-lanes
__global__ __launch_bounds__(256) void wsum_k(const float* __restrict__ af,
                                              const float* __restrict__ w,
                                              float* __restrict__ out) {
  __shared__ float wl[L_];
  __shared__ f32x4 part[256];
  int b = blockIdx.y;
  int lq = threadIdx.x >> 6;
  int dl = threadIdx.x & 63;
  int d4 = blockIdx.x * 64 + dl;
  if (threadIdx.x < L_) wl[threadIdx.x] = w[b * L_ + threadIdx.x];
  __syncthreads();
  f32x4 acc = {0.f, 0.f, 0.f, 0.f};
  int l0 = lq * 49;
  for (int l = l0; l < l0 + 49; ++l) {
    f32x4 v = *(const f32x4*)(af + (size_t)(b * L_ + l) * D_ + d4 * 4);
    acc += v * wl[l];
  }
  part[threadIdx.x] = acc;
  __syncthreads();
  if (threadIdx.x < 64) {
    f32x4 tot = part[threadIdx.x] + part[64 + threadIdx.x] +
                part[128 + threadIdx.x] + part[192 + threadIdx.x];
    *(f32x4*)(out + (size_t)b * D_ + d4 * 4) = tot;
  }
}

extern "C" void kernel_launch(void* const* d_in, const int* in_sizes, int n_in,
                              void* d_out, int out_size, void* d_ws, size_t ws_size,
                              hipStream_t stream) {
  const float* af    = (const float*)d_in[0];
  const float* h     = (const float*)d_in[1];
  const float* W_att = (const float*)d_in[2];
  const float* b_att = (const float*)d_in[3];
  const float* W_h   = (const float*)d_in[4];
  const float* b_h   = (const float*)d_in[5];
  const float* w_al  = (const float*)d_in[6];
  // b_alpha (d_in[7]) shifts all scores equally -> softmax-invariant -> unused.
  float* out = (float*)d_out;

  char* ws = (char*)d_ws;
  u16* WT       = (u16*)ws;                                   // 4 MiB
  float* ph     = (float*)(ws + (4u << 20));                  // 256 KiB
  float* scores = (float*)(ws + (4u << 20) + (256u << 10));   // 49 KiB

  hipMemsetAsync(ph, 0, (256u << 10) + M_ * sizeof(float), stream);
  transpose_w_k<<<dim3(32, 64), dim3(32, 8), 0, stream>>>(W_att, WT);
  ph_k<<<dim3(4, 8, 8), 256, 0, stream>>>(h, W_h, ph);
  gemm_score_k<<<dim3(8, 98), 256, 0, stream>>>(af, WT, ph, b_att, b_h, w_al, scores);
  softmax_k<<<64, 256, 0, stream>>>(scores, out + (size_t)B_ * D_);
  wsum_k<<<dim3(8, 64), 256, 0, stream>>>(af, out + (size_t)B_ * D_, out);
}

// Round 2
// 185.528 us; speedup vs baseline: 1.2825x; 1.2825x over previous
//
#include <hip/hip_runtime.h>

// Attention_22325240004782 — additive attention. B=64, L=196, D=2048, A=1024.
// R2: af pre-converted to bf16; GEMM uses m97 structure (global_load_lds x16,
// 128x128 BK=32, 2-barrier) + bijective XCD chunk remap for L2 locality.

typedef unsigned short u16;
typedef u16 u16x8 __attribute__((ext_vector_type(8)));
typedef __bf16 bf16x8 __attribute__((ext_vector_type(8)));
typedef float f32x4 __attribute__((ext_vector_type(4)));

#define B_ 64
#define L_ 196
#define D_ 2048
#define A_ 1024
#define M_ (B_ * L_)  // 12544 = 98 * 128

__device__ __forceinline__ u16 f2bf(float x) {
  unsigned u = __float_as_uint(x);
  unsigned r = (u + 0x7fffu + ((u >> 16) & 1u)) >> 16;  // RNE
  return (u16)r;
}

__device__ __forceinline__ float tanh_fast(float x) {
  float e = __expf(2.0f * x);
  return 1.0f - 2.0f / (e + 1.0f);
}

__device__ __forceinline__ void gload_lds16(const void* g, void* l) {
  __builtin_amdgcn_global_load_lds(
      (const __attribute__((address_space(1))) void*)g,
      (__attribute__((address_space(3))) void*)l, 16, 0, 0);
}

// ---- af fp32 -> bf16, 8 elems/thread ----
__global__ __launch_bounds__(256) void conv_af_k(const float* __restrict__ af,
                                                 u16* __restrict__ afb) {
  const size_t n = (size_t)M_ * D_;
  const size_t stride = (size_t)gridDim.x * blockDim.x * 8;
  for (size_t e = ((size_t)blockIdx.x * blockDim.x + threadIdx.x) * 8; e < n;
       e += stride) {
    float4 v0 = *(const float4*)(af + e);
    float4 v1 = *(const float4*)(af + e + 4);
    u16x8 p;
    p[0] = f2bf(v0.x); p[1] = f2bf(v0.y); p[2] = f2bf(v0.z); p[3] = f2bf(v0.w);
    p[4] = f2bf(v1.x); p[5] = f2bf(v1.y); p[6] = f2bf(v1.z); p[7] = f2bf(v1.w);
    *(u16x8*)(afb + e) = p;
  }
}

// ---- W_att [D][A] fp32 -> WT [A][D] bf16 ----
__global__ __launch_bounds__(256) void transpose_w_k(const float* __restrict__ W,
                                                     u16* __restrict__ WT) {
  __shared__ float t[32][33];
  int n0 = blockIdx.x * 32, k0 = blockIdx.y * 32;
  int tx = threadIdx.x, ty = threadIdx.y;  // 32 x 8
#pragma unroll
  for (int i = 0; i < 4; ++i)
    t[ty + i * 8][tx] = W[(size_t)(k0 + ty + i * 8) * A_ + n0 + tx];
  __syncthreads();
#pragma unroll
  for (int i = 0; i < 4; ++i)
    WT[(size_t)(n0 + ty + i * 8) * D_ + k0 + tx] = f2bf(t[tx][ty + i * 8]);
}

// ---- ph[b][a] = h @ W_h (biases folded into GEMM epilogue) ----
__global__ __launch_bounds__(256) void ph_k(const float* __restrict__ h,
                                            const float* __restrict__ Wh,
                                            float* __restrict__ ph) {
  __shared__ float hs[8 * 256];
  int ag = blockIdx.x, bg = blockIdx.y, dc = blockIdx.z;
  int t = threadIdx.x;
  int d0 = dc * 256;
  for (int i = t; i < 2048; i += 256)
    hs[i] = h[(size_t)(bg * 8 + (i >> 8)) * D_ + d0 + (i & 255)];
  __syncthreads();
  int a = ag * 256 + t;
  float acc[8] = {};
  for (int d = 0; d < 256; ++d) {
    float wv = Wh[(size_t)(d0 + d) * A_ + a];
#pragma unroll
    for (int bb = 0; bb < 8; ++bb) acc[bb] += hs[bb * 256 + d] * wv;
  }
#pragma unroll
  for (int bb = 0; bb < 8; ++bb)
    atomicAdd(&ph[(size_t)(bg * 8 + bb) * A_ + a], acc[bb]);
}

// ---- main GEMM (m97 structure): P = afb @ WT^T, fused tanh-score epilogue ----
// 128x128 tile, BK=32, 4 waves 2x2, global_load_lds x16, XCD chunk remap.
__global__ __launch_bounds__(256) void gemm_score2_k(
    const u16* __restrict__ afb, const u16* __restrict__ WT,
    const float* __restrict__ ph, const float* __restrict__ batt,
    const float* __restrict__ bh, const float* __restrict__ walpha,
    float* __restrict__ scores) {
  __shared__ u16 As[128 * 32];
  __shared__ u16 Bs[128 * 32];
  const int tid = threadIdx.x;
  const int lane = tid & 63;
  const int wid = tid >> 6;

  // bijective XCD chunk remap: 784 blocks, 8 XCDs, 98 per XCD.
  // XCD x handles virtual ids [98x, 98x+97] -> contiguous m-band, all n.
  int flat = blockIdx.x;
  int v = (flat & 7) * 98 + (flat >> 3);
  const int m0 = (v >> 3) * 128;
  const int n0 = (v & 7) * 128;

  const int wr = wid >> 1, wc = wid & 1;
  const int fr = lane & 15, fq = lane >> 4;

  // staging: tile = 128 rows x 32 k (64B/row) = 512 x 16B chunks, 2 rounds.
  // chunk c: row = c>>2, col8 = (c&3)*8. Wave-contiguous: c = r*256 + wid*64 + lane.
  const int c0 = wid * 64 + lane;
  const int r0row = c0 >> 2, r0col = (c0 & 3) * 8;
  const int r1row = 64 + r0row, r1col = r0col;  // c1 = c0 + 256 -> row += 64

  const u16* a0 = afb + (size_t)(m0 + r0row) * D_ + r0col;
  const u16* a1 = afb + (size_t)(m0 + r1row) * D_ + r1col;
  const u16* b0 = WT + (size_t)(n0 + r0row) * D_ + r0col;
  const u16* b1 = WT + (size_t)(n0 + r1row) * D_ + r1col;
  u16* asd0 = &As[wid * 512];         // wave-uniform LDS bases
  u16* asd1 = &As[2048 + wid * 512];
  u16* bsd0 = &Bs[wid * 512];
  u16* bsd1 = &Bs[2048 + wid * 512];

  f32x4 acc[4][4] = {};

  for (int k0 = 0; k0 < D_; k0 += 32) {
    gload_lds16(a0 + k0, asd0);
    gload_lds16(a1 + k0, asd1);
    gload_lds16(b0 + k0, bsd0);
    gload_lds16(b1 + k0, bsd1);
    __syncthreads();  // compiler emits vmcnt(0) drain before barrier
    u16x8 arg[4], brg[4];
#pragma unroll
    for (int mi = 0; mi < 4; ++mi)
      arg[mi] = *(const u16x8*)&As[(wr * 64 + mi * 16 + fr) * 32 + fq * 8];
#pragma unroll
    for (int ni = 0; ni < 4; ++ni)
      brg[ni] = *(const u16x8*)&Bs[(wc * 64 + ni * 16 + fr) * 32 + fq * 8];
#pragma unroll
    for (int mi = 0; mi < 4; ++mi)
#pragma unroll
      for (int ni = 0; ni < 4; ++ni)
        acc[mi][ni] = __builtin_amdgcn_mfma_f32_16x16x32_bf16(
            __builtin_bit_cast(bf16x8, arg[mi]),
            __builtin_bit_cast(bf16x8, brg[ni]), acc[mi][ni], 0, 0, 0);
    __syncthreads();
  }

  // epilogue: p = acc + ph[b] + b_att + b_h; score partial = tanh(p)*w_alpha
#pragma unroll
  for (int mi = 0; mi < 4; ++mi) {
#pragma unroll
    for (int r = 0; r < 4; ++r) {
      const int gm = m0 + wr * 64 + mi * 16 + fq * 4 + r;
      const int bb = gm / L_;
      const float* phrow = ph + (size_t)bb * A_;
      float sp = 0.f;
#pragma unroll
      for (int ni = 0; ni < 4; ++ni) {
        const int gn = n0 + wc * 64 + ni * 16 + fr;
        float p = acc[mi][ni][r] + phrow[gn] + batt[gn] + bh[gn];
        sp += tanh_fast(p) * walpha[gn];
      }
      sp += __shfl_xor(sp, 1);
      sp += __shfl_xor(sp, 2);
      sp += __shfl_xor(sp, 4);
      sp += __shfl_xor(sp, 8);
      if (fr == 0) atomicAdd(&scores[gm], sp);
    }
  }
}

// ---- fallback GEMM (round-1, reg-staged fp32 A) for small ws ----
__global__ __launch_bounds__(256) void gemm_score_fb_k(
    const float* __restrict__ af, const u16* __restrict__ WT,
    const float* __restrict__ ph, const float* __restrict__ batt,
    const float* __restrict__ bh, const float* __restrict__ walpha,
    float* __restrict__ scores) {
  __shared__ u16 As[128 * 32];
  __shared__ u16 Bs[128 * 32];
  const int tid = threadIdx.x;
  const int lane = tid & 63;
  const int wid = tid >> 6;
  const int wr = wid >> 1, wc = wid & 1;
  const int m0 = blockIdx.y * 128;
  const int n0 = blockIdx.x * 128;
  const int fr = lane & 15, fq = lane >> 4;
  f32x4 acc[4][4] = {};
  const int ar = tid >> 3, akq = tid & 7;
  const int br = tid >> 2, bkc = tid & 3;
  const float* aptr = af + (size_t)(m0 + ar) * D_ + akq * 4;
  const u16* bptr = WT + (size_t)(n0 + br) * D_ + bkc * 8;
  for (int k0 = 0; k0 < D_; k0 += 32) {
#pragma unroll
    for (int i = 0; i < 4; ++i) {
      float4 vv = *(const float4*)(aptr + (size_t)i * 32 * D_ + k0);
      ushort4 p;
      p.x = f2bf(vv.x); p.y = f2bf(vv.y); p.z = f2bf(vv.z); p.w = f2bf(vv.w);
      *(ushort4*)&As[(ar + i * 32) * 32 + akq * 4] = p;
    }
#pragma unroll
    for (int i = 0; i < 2; ++i) {
      u16x8 vv = *(const u16x8*)(bptr + (size_t)i * 64 * D_ + k0);
      *(u16x8*)&Bs[(br + i * 64) * 32 + bkc * 8] = vv;
    }
    __syncthreads();
    u16x8 arg[4], brg[4];
#pragma unroll
    for (int mi = 0; mi < 4; ++mi)
      arg[mi] = *(const u16x8*)&As[(wr * 64 + mi * 16 + fr) * 32 + fq * 8];
#pragma unroll
    for (int ni = 0; ni < 4; ++ni)
      brg[ni] = *(const u16x8*)&Bs[(wc * 64 + ni * 16 + fr) * 32 + fq * 8];
#pragma unroll
    for (int mi = 0; mi < 4; ++mi)
#pragma unroll
      for (int ni = 0; ni < 4; ++ni)
        acc[mi][ni] = __builtin_amdgcn_mfma_f32_16x16x32_bf16(
            __builtin_bit_cast(bf16x8, arg[mi]),
            __builtin_bit_cast(bf16x8, brg[ni]), acc[mi][ni], 0, 0, 0);
    __syncthreads();
  }
#pragma unroll
  for (int mi = 0; mi < 4; ++mi) {
#pragma unroll
    for (int r = 0; r < 4; ++r) {
      const int gm = m0 + wr * 64 + mi * 16 + fq * 4 + r;
      const int bb = gm / L_;
      const float* phrow = ph + (size_t)bb * A_;
      float sp = 0.f;
#pragma unroll
      for (int ni = 0; ni < 4; ++ni) {
        const int gn = n0 + wc * 64 + ni * 16 + fr;
        float p = acc[mi][ni][r] + phrow[gn] + batt[gn] + bh[gn];
        sp += tanh_fast(p) * walpha[gn];
      }
      sp += __shfl_xor(sp, 1);
      sp += __shfl_xor(sp, 2);
      sp += __shfl_xor(sp, 4);
      sp += __shfl_xor(sp, 8);
      if (fr == 0) atomicAdd(&scores[gm], sp);
    }
  }
}

// ---- softmax over L=196 per batch ----
__global__ __launch_bounds__(256) void softmax_k(const float* __restrict__ scores,
                                                 float* __restrict__ wout) {
  __shared__ float red[4];
  int b = blockIdx.x, t = threadIdx.x;
  float s = (t < L_) ? scores[b * L_ + t] : -1e30f;
  float m = s;
#pragma unroll
  for (int o = 32; o; o >>= 1) m = fmaxf(m, __shfl_xor(m, o));
  if ((t & 63) == 0) red[t >> 6] = m;
  __syncthreads();
  m = fmaxf(fmaxf(red[0], red[1]), fmaxf(red[2], red[3]));
  float e = (t < L_) ? __expf(s - m) : 0.f;
  float sum = e;
#pragma unroll
  for (int o = 32; o; o >>= 1) sum += __shfl_xor(sum, o);
  __syncthreads();
  if ((t & 63) == 0) red[t >> 6] = sum;
  __syncthreads();
  sum = red[0] + red[1] + red[2] + red[3];
  if (t < L_) wout[b * L_ + t] = e / sum;
}

// ---- weighted[b][d] = sum_l w[b][l] * af[b][l][d] ----
__global__ __launch_bounds__(256) void wsum_k(const float* __restrict__ af,
                                              const float* __restrict__ w,
                                              float* __restrict__ out) {
  __shared__ float wl[L_];
  __shared__ f32x4 part[256];
  int b = blockIdx.y;
  int lq = threadIdx.x >> 6;
  int dl = threadIdx.x & 63;
  int d4 = blockIdx.x * 64 + dl;
  if (threadIdx.x < L_) wl[threadIdx.x] = w[b * L_ + threadIdx.x];
  __syncthreads();
  f32x4 acc = {0.f, 0.f, 0.f, 0.f};
  int l0 = lq * 49;
  for (int l = l0; l < l0 + 49; ++l) {
    f32x4 vv = *(const f32x4*)(af + (size_t)(b * L_ + l) * D_ + d4 * 4);
    acc += vv * wl[l];
  }
  part[threadIdx.x] = acc;
  __syncthreads();
  if (threadIdx.x < 64) {
    f32x4 tot = part[threadIdx.x] + part[64 + threadIdx.x] +
                part[128 + threadIdx.x] + part[192 + threadIdx.x];
    *(f32x4*)(out + (size_t)b * D_ + d4 * 4) = tot;
  }
}

extern "C" void kernel_launch(void* const* d_in, const int* in_sizes, int n_in,
                              void* d_out, int out_size, void* d_ws, size_t ws_size,
                              hipStream_t stream) {
  const float* af    = (const float*)d_in[0];
  const float* h     = (const float*)d_in[1];
  const float* W_att = (const float*)d_in[2];
  const float* b_att = (const float*)d_in[3];
  const float* W_h   = (const float*)d_in[4];
  const float* b_h   = (const float*)d_in[5];
  const float* w_al  = (const float*)d_in[6];
  float* out = (float*)d_out;
  char* ws = (char*)d_ws;

  const size_t AFB_OFF = 0;                        // 51.4 MB bf16 af
  const size_t WT_OFF  = 0x3200000;                // 4 MB
  const size_t PH_OFF  = 0x3600000;                // 256 KB
  const size_t SC_OFF  = 0x3640000;                // 200 KB
  const size_t NEED    = SC_OFF + (size_t)M_ * sizeof(float);

  if (ws_size >= NEED) {
    u16* afb      = (u16*)(ws + AFB_OFF);
    u16* WT       = (u16*)(ws + WT_OFF);
    float* ph     = (float*)(ws + PH_OFF);
    float* scores = (float*)(ws + SC_OFF);
    hipMemsetAsync(ph, 0, (256u << 10) + (size_t)M_ * sizeof(float), stream);
    conv_af_k<<<2048, 256, 0, stream>>>(af, afb);
    transpose_w_k<<<dim3(32, 64), dim3(32, 8), 0, stream>>>(W_att, WT);
    ph_k<<<dim3(4, 8, 8), 256, 0, stream>>>(h, W_h, ph);
    gemm_score2_k<<<784, 256, 0, stream>>>(afb, WT, ph, b_att, b_h, w_al, scores);
    softmax_k<<<64, 256, 0, stream>>>(scores, out + (size_t)B_ * D_);
    wsum_k<<<dim3(8, 64), 256, 0, stream>>>(af, out + (size_t)B_ * D_, out);
  } else {
    u16* WT       = (u16*)ws;
    float* ph     = (float*)(ws + (4u << 20));
    float* scores = (float*)(ws + (4u << 20) + (256u << 10));
    hipMemsetAsync(ph, 0, (256u << 10) + (size_t)M_ * sizeof(float), stream);
    transpose_w_k<<<dim3(32, 64), dim3(32, 8), 0, stream>>>(W_att, WT);
    ph_k<<<dim3(4, 8, 8), 256, 0, stream>>>(h, W_h, ph);
    gemm_score_fb_k<<<dim3(8, 98), 256, 0, stream>>>(af, WT, ph, b_att, b_h, w_al, scores);
    softmax_k<<<64, 256, 0, stream>>>(scores, out + (size_t)B_ * D_);
    wsum_k<<<dim3(8, 64), 256, 0, stream>>>(af, out + (size_t)B_ * D_, out);
  }
}

// Round 3
// 149.474 us; speedup vs baseline: 1.5918x; 1.2412x over previous
//
#include <hip/hip_runtime.h>

// Attention_22325240004782 — additive attention. B=64, L=196, D=2048, A=1024.
// R3: 256x256 8-phase GEMM (T2 st_16x32 swizzle + T3/T4 counted vmcnt + T5
// setprio), XCD bijective remap; wsum reads bf16 af.

typedef unsigned short u16;
typedef u16 u16x8 __attribute__((ext_vector_type(8)));
typedef __bf16 bf16x8 __attribute__((ext_vector_type(8)));
typedef float f32x4 __attribute__((ext_vector_type(4)));

#define B_ 64
#define L_ 196
#define D_ 2048
#define A_ 1024
#define M_ (B_ * L_)  // 12544 = 49 * 256
#define NT 32         // K tiles of 64

__device__ __forceinline__ u16 f2bf(float x) {
  unsigned u = __float_as_uint(x);
  unsigned r = (u + 0x7fffu + ((u >> 16) & 1u)) >> 16;  // RNE
  return (u16)r;
}

__device__ __forceinline__ float tanh_fast(float x) {
  float e = __expf(2.0f * x);
  return 1.0f - 2.0f / (e + 1.0f);
}

__device__ __forceinline__ void gload_lds16(const void* g, void* l) {
  __builtin_amdgcn_global_load_lds(
      (const __attribute__((address_space(1))) void*)g,
      (__attribute__((address_space(3))) void*)l, 16, 0, 0);
}

// ---- af fp32 -> bf16 ----
__global__ __launch_bounds__(256) void conv_af_k(const float* __restrict__ af,
                                                 u16* __restrict__ afb) {
  const size_t n = (size_t)M_ * D_;
  const size_t stride = (size_t)gridDim.x * blockDim.x * 8;
  for (size_t e = ((size_t)blockIdx.x * blockDim.x + threadIdx.x) * 8; e < n;
       e += stride) {
    float4 v0 = *(const float4*)(af + e);
    float4 v1 = *(const float4*)(af + e + 4);
    u16x8 p;
    p[0] = f2bf(v0.x); p[1] = f2bf(v0.y); p[2] = f2bf(v0.z); p[3] = f2bf(v0.w);
    p[4] = f2bf(v1.x); p[5] = f2bf(v1.y); p[6] = f2bf(v1.z); p[7] = f2bf(v1.w);
    *(u16x8*)(afb + e) = p;
  }
}

// ---- W_att [D][A] fp32 -> WT [A][D] bf16 ----
__global__ __launch_bounds__(256) void transpose_w_k(const float* __restrict__ W,
                                                     u16* __restrict__ WT) {
  __shared__ float t[32][33];
  int n0 = blockIdx.x * 32, k0 = blockIdx.y * 32;
  int tx = threadIdx.x, ty = threadIdx.y;  // 32 x 8
#pragma unroll
  for (int i = 0; i < 4; ++i)
    t[ty + i * 8][tx] = W[(size_t)(k0 + ty + i * 8) * A_ + n0 + tx];
  __syncthreads();
#pragma unroll
  for (int i = 0; i < 4; ++i)
    WT[(size_t)(n0 + ty + i * 8) * D_ + k0 + tx] = f2bf(t[tx][ty + i * 8]);
}

// ---- ph[b][a] = h @ W_h ----
__global__ __launch_bounds__(256) void ph_k(const float* __restrict__ h,
                                            const float* __restrict__ Wh,
                                            float* __restrict__ ph) {
  __shared__ float hs[8 * 256];
  int ag = blockIdx.x, bg = blockIdx.y, dc = blockIdx.z;
  int t = threadIdx.x;
  int d0 = dc * 256;
  for (int i = t; i < 2048; i += 256)
    hs[i] = h[(size_t)(bg * 8 + (i >> 8)) * D_ + d0 + (i & 255)];
  __syncthreads();
  int a = ag * 256 + t;
  float acc[8] = {};
  for (int d = 0; d < 256; ++d) {
    float wv = Wh[(size_t)(d0 + d) * A_ + a];
#pragma unroll
    for (int bb = 0; bb < 8; ++bb) acc[bb] += hs[bb * 256 + d] * wv;
  }
#pragma unroll
  for (int bb = 0; bb < 8; ++bb)
    atomicAdd(&ph[(size_t)(bg * 8 + bb) * A_ + a], acc[bb]);
}

// ==== 256x256x(BK=64) 8-phase GEMM with fused tanh-score epilogue ====
// 512 thr = 8 waves (2M x 4N). Wave output 128x64. LDS 128 KiB (2 buf x 2
// half x [128][64] bf16 per operand). st_16x32 swizzle: tile stored as
// subtiles [sr 0..7][sc 0..1] of 16 rows x 32 cols (1024 B); within a
// subtile, rows 8-15 XOR byte-bit5. Stage source pre-swizzled to match
// linear global_load_lds dest (both-sides rule).
__global__ __launch_bounds__(512, 2) void gemm8_k(
    const u16* __restrict__ afb, const u16* __restrict__ WT,
    const float* __restrict__ ph, const float* __restrict__ batt,
    const float* __restrict__ bh, const float* __restrict__ walpha,
    float* __restrict__ scores) {
  __shared__ __align__(16) u16 As[2][2][8192];
  __shared__ __align__(16) u16 Bs[2][2][8192];
  const int tid = threadIdx.x;
  const int lane = tid & 63;
  const int wid = tid >> 6;
  const int wr = wid >> 2;   // 0..1 (M)
  const int wc = wid & 3;    // 0..3 (N)
  const int wchalf = wc >> 1, wcl = wc & 1;
  const int fr = lane & 15, fq = lane >> 4;

  // bijective XCD remap: 196 blocks, q=24, r=4
  const int xcd = blockIdx.x & 7, idx = blockIdx.x >> 3;
  const int wg = (xcd < 4 ? xcd * 25 : 100 + (xcd - 4) * 24) + idx;
  const int m0 = (wg >> 2) * 256;
  const int n0 = (wg & 3) * 256;

  // staging geometry: chunk c = r*512 + tid; maps to (row,col) of the
  // [128][64] half-tile under the swizzled layout.
  int rowc[2], colc[2];
#pragma unroll
  for (int r = 0; r < 2; ++r) {
    int c = r * 512 + tid;
    int s = c >> 6, cw = c & 63;
    rowc[r] = (s >> 1) * 16 + (cw >> 2);
    colc[r] = (s & 1) * 32 + ((((cw & 3) * 16) ^ (((cw >> 5) & 1) * 32)) >> 1);
  }
  const u16* srcA[2][2];
  const u16* srcB[2][2];
#pragma unroll
  for (int hh = 0; hh < 2; ++hh)
#pragma unroll
    for (int r = 0; r < 2; ++r) {
      srcA[hh][r] = afb + (size_t)(m0 + hh * 128 + rowc[r]) * D_ + colc[r];
      srcB[hh][r] = WT + (size_t)(n0 + hh * 128 + rowc[r]) * D_ + colc[r];
    }

  // swizzled lane byte offset for ds_read_b128 fragment reads
  const int laneA = (lane & 15) * 64 + (((lane >> 4) * 16) ^ ((lane & 8) << 2));

  f32x4 acc[8][4] = {};
  u16x8 areg[4][2], breg[4][2];

#define STG_A(BUF, H, KT)                                                    \
  do {                                                                       \
    gload_lds16(srcA[H][0] + (size_t)(KT) * 64, &As[BUF][H][wid * 512]);     \
    gload_lds16(srcA[H][1] + (size_t)(KT) * 64, &As[BUF][H][4096 + wid * 512]); \
  } while (0)
#define STG_B(BUF, H, KT)                                                    \
  do {                                                                       \
    gload_lds16(srcB[H][0] + (size_t)(KT) * 64, &Bs[BUF][H][wid * 512]);     \
    gload_lds16(srcB[H][1] + (size_t)(KT) * 64, &Bs[BUF][H][4096 + wid * 512]); \
  } while (0)
#define LDA_HALF(BF, MH)                                                     \
  do {                                                                       \
    _Pragma("unroll") for (int q = 0; q < 4; ++q) {                          \
      areg[q][0] = *(const u16x8*)&As[BF][wr][((((MH)*4 + q) * 2 + 0) * 1024 + laneA) >> 1]; \
      areg[q][1] = *(const u16x8*)&As[BF][wr][((((MH)*4 + q) * 2 + 1) * 1024 + laneA) >> 1]; \
    }                                                                        \
  } while (0)
#define LDB_PAIR(BF, NQ)                                                     \
  do {                                                                       \
    _Pragma("unroll") for (int nn = 0; nn < 2; ++nn) {                       \
      breg[(NQ)*2 + nn][0] = *(const u16x8*)&Bs[BF][wchalf][(((wcl * 4 + (NQ)*2 + nn) * 2 + 0) * 1024 + laneA) >> 1]; \
      breg[(NQ)*2 + nn][1] = *(const u16x8*)&Bs[BF][wchalf][(((wcl * 4 + (NQ)*2 + nn) * 2 + 1) * 1024 + laneA) >> 1]; \
    }                                                                        \
  } while (0)
#define MM_QUAD(MH, NQ)                                                      \
  do {                                                                       \
    _Pragma("unroll") for (int q = 0; q < 4; ++q)                            \
    _Pragma("unroll") for (int nn = 0; nn < 2; ++nn)                         \
    _Pragma("unroll") for (int kh = 0; kh < 2; ++kh)                         \
      acc[(MH)*4 + q][(NQ)*2 + nn] = __builtin_amdgcn_mfma_f32_16x16x32_bf16( \
          __builtin_bit_cast(bf16x8, areg[q][kh]),                           \
          __builtin_bit_cast(bf16x8, breg[(NQ)*2 + nn][kh]),                 \
          acc[(MH)*4 + q][(NQ)*2 + nn], 0, 0, 0);                            \
  } while (0)
#define PH_PRE()                                                             \
  do {                                                                       \
    __builtin_amdgcn_s_barrier();                                            \
    asm volatile("s_waitcnt lgkmcnt(0)" ::: "memory");                       \
    __builtin_amdgcn_s_setprio(1);                                           \
  } while (0)
#define PH_POST()                                                            \
  do {                                                                       \
    __builtin_amdgcn_s_setprio(0);                                           \
    __builtin_amdgcn_s_barrier();                                            \
  } while (0)
// MODE: 0 = steady (stage t+1.A1 + t+2.{B0,B1,A0}, vmcnt(6))
//       1 = tail-1 (stage t+1.A1 only, vmcnt(0));  2 = last (nothing)
#define KTILE(BF, T, MODE)                                                   \
  do {                                                                       \
    LDA_HALF(BF, 0); LDB_PAIR(BF, 0);                                        \
    if ((MODE) <= 1) STG_A((BF) ^ 1, 1, (T) + 1);                            \
    PH_PRE(); MM_QUAD(0, 0); PH_POST();                                      \
    LDB_PAIR(BF, 1);                                                         \
    if ((MODE) == 0) STG_B(BF, 0, (T) + 2);                                  \
    PH_PRE(); MM_QUAD(0, 1); PH_POST();                                      \
    LDA_HALF(BF, 1);                                                         \
    if ((MODE) == 0) STG_B(BF, 1, (T) + 2);                                  \
    PH_PRE(); MM_QUAD(1, 0); PH_POST();                                      \
    if ((MODE) == 0) STG_A(BF, 0, (T) + 2);                                  \
    PH_PRE(); MM_QUAD(1, 1);                                                 \
    __builtin_amdgcn_s_setprio(0);                                           \
    if ((MODE) == 0) asm volatile("s_waitcnt vmcnt(6)" ::: "memory");        \
    if ((MODE) == 1) asm volatile("s_waitcnt vmcnt(0)" ::: "memory");        \
    __builtin_amdgcn_s_barrier();                                            \
  } while (0)

  // prologue: tile0 fully + tile1 {B0,B1,A0}; FIFO leaves 3 HTs outstanding
  STG_B(0, 0, 0); STG_B(0, 1, 0); STG_A(0, 0, 0); STG_A(0, 1, 0);
  asm volatile("s_waitcnt vmcnt(4)" ::: "memory");
  STG_B(1, 0, 1); STG_B(1, 1, 1); STG_A(1, 0, 1);
  asm volatile("s_waitcnt vmcnt(6)" ::: "memory");
  __builtin_amdgcn_s_barrier();

#pragma unroll 1
  for (int it = 0; it < 15; ++it) {
    const int t = it * 2;
    KTILE(0, t, 0);
    KTILE(1, t + 1, 0);
  }
  KTILE(0, 30, 1);
  KTILE(1, 31, 2);

  // epilogue: p = acc + ph[b] + b_att + b_h; score partial = tanh(p)*w_alpha
#pragma unroll
  for (int mi = 0; mi < 8; ++mi) {
#pragma unroll
    for (int rr = 0; rr < 4; ++rr) {
      const int gm = m0 + wr * 128 + mi * 16 + fq * 4 + rr;
      const int bb = gm / L_;
      const float* phrow = ph + (size_t)bb * A_;
      float sp = 0.f;
#pragma unroll
      for (int ni = 0; ni < 4; ++ni) {
        const int gn = n0 + wc * 64 + ni * 16 + fr;
        float p = acc[mi][ni][rr] + phrow[gn] + batt[gn] + bh[gn];
        sp += tanh_fast(p) * walpha[gn];
      }
      sp += __shfl_xor(sp, 1);
      sp += __shfl_xor(sp, 2);
      sp += __shfl_xor(sp, 4);
      sp += __shfl_xor(sp, 8);
      if (fr == 0) atomicAdd(&scores[gm], sp);
    }
  }
}

// ---- softmax over L=196 per batch ----
__global__ __launch_bounds__(256) void softmax_k(const float* __restrict__ scores,
                                                 float* __restrict__ wout) {
  __shared__ float red[4];
  int b = blockIdx.x, t = threadIdx.x;
  float s = (t < L_) ? scores[b * L_ + t] : -1e30f;
  float m = s;
#pragma unroll
  for (int o = 32; o; o >>= 1) m = fmaxf(m, __shfl_xor(m, o));
  if ((t & 63) == 0) red[t >> 6] = m;
  __syncthreads();
  m = fmaxf(fmaxf(red[0], red[1]), fmaxf(red[2], red[3]));
  float e = (t < L_) ? __expf(s - m) : 0.f;
  float sum = e;
#pragma unroll
  for (int o = 32; o; o >>= 1) sum += __shfl_xor(sum, o);
  __syncthreads();
  if ((t & 63) == 0) red[t >> 6] = sum;
  __syncthreads();
  sum = red[0] + red[1] + red[2] + red[3];
  if (t < L_) wout[b * L_ + t] = e / sum;
}

// ---- weighted[b][d] = sum_l w[b][l] * afb[b][l][d] (bf16 read) ----
__global__ __launch_bounds__(256) void wsum_k(const u16* __restrict__ afb,
                                              const float* __restrict__ w,
                                              float* __restrict__ out) {
  __shared__ float wl[256];
  __shared__ float part[256][8];
  int b = blockIdx.y;
  int lq = threadIdx.x >> 6;
  int dl = threadIdx.x & 63;
  int d8 = blockIdx.x * 64 + dl;  // 8-elem group, 0..255
  wl[threadIdx.x] = (threadIdx.x < L_) ? w[b * L_ + threadIdx.x] : 0.f;
  __syncthreads();
  float acc[8] = {};
  for (int l = lq * 49; l < lq * 49 + 49; ++l) {
    u16x8 v = *(const u16x8*)(afb + (size_t)(b * L_ + l) * D_ + d8 * 8);
    float ww = wl[l];
#pragma unroll
    for (int j = 0; j < 8; ++j)
      acc[j] += ww * __uint_as_float((unsigned)v[j] << 16);
  }
#pragma unroll
  for (int j = 0; j < 8; ++j) part[threadIdx.x][j] = acc[j];
  __syncthreads();
  if (threadIdx.x < 64) {
    float4 o0, o1;
    o0.x = part[dl][0] + part[64 + dl][0] + part[128 + dl][0] + part[192 + dl][0];
    o0.y = part[dl][1] + part[64 + dl][1] + part[128 + dl][1] + part[192 + dl][1];
    o0.z = part[dl][2] + part[64 + dl][2] + part[128 + dl][2] + part[192 + dl][2];
    o0.w = part[dl][3] + part[64 + dl][3] + part[128 + dl][3] + part[192 + dl][3];
    o1.x = part[dl][4] + part[64 + dl][4] + part[128 + dl][4] + part[192 + dl][4];
    o1.y = part[dl][5] + part[64 + dl][5] + part[128 + dl][5] + part[192 + dl][5];
    o1.z = part[dl][6] + part[64 + dl][6] + part[128 + dl][6] + part[192 + dl][6];
    o1.w = part[dl][7] + part[64 + dl][7] + part[128 + dl][7] + part[192 + dl][7];
    *(float4*)(out + (size_t)b * D_ + d8 * 8) = o0;
    *(float4*)(out + (size_t)b * D_ + d8 * 8 + 4) = o1;
  }
}

extern "C" void kernel_launch(void* const* d_in, const int* in_sizes, int n_in,
                              void* d_out, int out_size, void* d_ws, size_t ws_size,
                              hipStream_t stream) {
  const float* af    = (const float*)d_in[0];
  const float* h     = (const float*)d_in[1];
  const float* W_att = (const float*)d_in[2];
  const float* b_att = (const float*)d_in[3];
  const float* W_h   = (const float*)d_in[4];
  const float* b_h   = (const float*)d_in[5];
  const float* w_al  = (const float*)d_in[6];
  float* out = (float*)d_out;
  char* ws = (char*)d_ws;

  u16* afb      = (u16*)ws;                       // 51.4 MB
  u16* WT       = (u16*)(ws + 0x3200000);         // 4 MB
  float* ph     = (float*)(ws + 0x3600000);       // 256 KB
  float* scores = (float*)(ws + 0x3640000);       // 50 KB

  hipMemsetAsync(ph, 0, (256u << 10) + (size_t)M_ * sizeof(float), stream);
  conv_af_k<<<2048, 256, 0, stream>>>(af, afb);
  transpose_w_k<<<dim3(32, 64), dim3(32, 8), 0, stream>>>(W_att, WT);
  ph_k<<<dim3(4, 8, 8), 256, 0, stream>>>(h, W_h, ph);
  gemm8_k<<<196, 512, 0, stream>>>(afb, WT, ph, b_att, b_h, w_al, scores);
  softmax_k<<<64, 256, 0, stream>>>(scores, out + (size_t)B_ * D_);
  wsum_k<<<dim3(4, 64), 256, 0, stream>>>(afb, out + (size_t)B_ * D_, out);
}